// Round 1
// baseline (301.448 us; speedup 1.0000x reference)
//
#include <hip/hip_runtime.h>
#include <hip/hip_bf16.h>

// Problem constants (from reference)
#define NF 10          // NUM_FEATURES
#define EMB 256        // EMBED_DIM
#define TOK (256*512)  // B*S = 131072 tokens
#define OUTW 512       // 2*EMBED_DIM per token

// Block = 256 threads = 4 waves. Per iteration a block covers 2 tokens:
//   threadIdx 0..127   -> token base+0,  threadIdx 128..255 -> token base+1
//   q = t & 127: q<64  -> obs-embed float4 (e = 4q)        [waves 0, 2]
//                q>=64 -> pos-embed float4 (e = 4(q-64))   [waves 1, 3]
// Role is wave-uniform -> no divergence. Obs threads hold their 4 W rows +
// bias in registers across the whole grid-stride loop; PE threads hold their
// two div_term constants and evaluate sin/cos inline (no 375KB table, no ws).
__global__ __launch_bounds__(256) void bert_embed_kernel(
    const float* __restrict__ x,    // [TOK, NF]
    const int*   __restrict__ doy,  // [TOK]
    const float* __restrict__ W,    // [EMB, NF]
    const float* __restrict__ bias, // [EMB]
    float*       __restrict__ out)  // [TOK, OUTW]
{
    const int t          = threadIdx.x;
    const int tok_in_blk = t >> 7;    // 0 or 1
    const int q          = t & 127;   // quad index within token
    const bool is_obs    = (q < 64);  // uniform per wave

    // ---- per-thread loop-invariant state ----
    float w[4][NF];
    float bv[4];
    float dv0 = 0.f, dv1 = 0.f;
    if (is_obs) {
        const int e0 = q * 4;
        #pragma unroll
        for (int r = 0; r < 4; ++r) {
            #pragma unroll
            for (int f = 0; f < NF; ++f) w[r][f] = W[(e0 + r) * NF + f];
            bv[r] = bias[e0 + r];
        }
    } else {
        const int e0 = (q - 64) * 4;  // even element base
        const float c = -9.210340371976184f / 256.0f;  // -ln(10000)/EMBED_DIM
        dv0 = expf((float)e0 * c);
        dv1 = expf((float)(e0 + 2) * c);
    }

    const int stride = gridDim.x * 2;
    for (int tok = blockIdx.x * 2 + tok_in_blk; tok < TOK; tok += stride) {
        float4 o;
        if (is_obs) {
            // x row is wave-uniform -> scalar loads / L1 broadcast
            const float* xp = x + (long long)tok * NF;
            float xv[NF];
            #pragma unroll
            for (int f = 0; f < NF; ++f) xv[f] = xp[f];
            #pragma unroll
            for (int r = 0; r < 4; ++r) {
                float acc = bv[r];
                #pragma unroll
                for (int f = 0; f < NF; ++f) acc = fmaf(w[r][f], xv[f], acc);
                (&o.x)[r] = acc;
            }
            *(float4*)(out + (long long)tok * OUTW + q * 4) = o;
        } else {
            const int d = doy[tok];           // wave-uniform
            if (d == 0) {
                o = make_float4(0.f, 0.f, 0.f, 0.f);  // pe row 0 is zeros
            } else {
                const float pos = (float)(d - 1);
                const float a0 = pos * dv0;
                const float a1 = pos * dv1;
                o.x = sinf(a0); o.y = cosf(a0);
                o.z = sinf(a1); o.w = cosf(a1);
            }
            *(float4*)(out + (long long)tok * OUTW + EMB + (q - 64) * 4) = o;
        }
    }
}

extern "C" void kernel_launch(void* const* d_in, const int* in_sizes, int n_in,
                              void* d_out, int out_size, void* d_ws, size_t ws_size,
                              hipStream_t stream) {
    const float* x    = (const float*)d_in[0];  // input_sequence [B,S,NF] fp32
    const int*   doy  = (const int*)  d_in[1];  // doy_sequence   [B,S]    int32
    const float* W    = (const float*)d_in[2];  // W [EMB,NF] fp32
    const float* bias = (const float*)d_in[3];  // b [EMB]    fp32
    float*       out  = (float*)d_out;          // [B,S,2*EMB] fp32

    // 2048 blocks (8/CU) x 4 waves = full occupancy for a write-bound stream;
    // each block covers 2 tokens/iter -> 32 grid-stride iterations.
    bert_embed_kernel<<<2048, 256, 0, stream>>>(x, doy, W, bias, out);
}

// Round 2
// 298.695 us; speedup vs baseline: 1.0092x; 1.0092x over previous
//
#include <hip/hip_runtime.h>
#include <hip/hip_bf16.h>

// Problem constants (from reference)
#define NF 10          // NUM_FEATURES
#define EMB 256        // EMBED_DIM
#define TOK (256*512)  // B*S = 131072 tokens
#define OUTW 512       // 2*EMBED_DIM per token

// Block = 256 threads = 4 waves. Per iteration a block covers 2 tokens:
//   threadIdx 0..127   -> token base+0,  threadIdx 128..255 -> token base+1
//   q = t & 127: q<64  -> obs-embed float4 (e = 4q)        [waves 0, 2]
//                q>=64 -> pos-embed float4 (e = 4(q-64))   [waves 1, 3]
// Role is wave-uniform -> no divergence. Obs threads hold their 4 W rows +
// bias in registers across the whole grid-stride loop; PE threads hold their
// two div_term constants and evaluate HW sin/cos (v_sin_f32/v_cos_f32 via
// __sinf/__cosf — libm sinf was ~350 VALU instr/call and made R0 trig-bound
// at 301 us vs the ~43 us write floor).
__global__ __launch_bounds__(256) void bert_embed_kernel(
    const float* __restrict__ x,    // [TOK, NF]
    const int*   __restrict__ doy,  // [TOK]
    const float* __restrict__ W,    // [EMB, NF]
    const float* __restrict__ bias, // [EMB]
    float*       __restrict__ out)  // [TOK, OUTW]
{
    const int t          = threadIdx.x;
    const int tok_in_blk = t >> 7;    // 0 or 1
    const int q          = t & 127;   // quad index within token
    const bool is_obs    = (q < 64);  // uniform per wave

    // ---- per-thread loop-invariant state ----
    float w[4][NF];
    float bv[4];
    float dv0 = 0.f, dv1 = 0.f;
    if (is_obs) {
        const int e0 = q * 4;
        #pragma unroll
        for (int r = 0; r < 4; ++r) {
            #pragma unroll
            for (int f = 0; f < NF; ++f) w[r][f] = W[(e0 + r) * NF + f];
            bv[r] = bias[e0 + r];
        }
    } else {
        const int e0 = (q - 64) * 4;  // even element base
        const float c = -9.210340371976184f / 256.0f;  // -ln(10000)/EMBED_DIM
        dv0 = __expf((float)e0 * c);
        dv1 = __expf((float)(e0 + 2) * c);
    }

    const int stride = gridDim.x * 2;
    for (int tok = blockIdx.x * 2 + tok_in_blk; tok < TOK; tok += stride) {
        float4 o;
        if (is_obs) {
            // x row is wave-uniform -> L1 broadcast
            const float* xp = x + (long long)tok * NF;
            float xv[NF];
            #pragma unroll
            for (int f = 0; f < NF; ++f) xv[f] = xp[f];
            #pragma unroll
            for (int r = 0; r < 4; ++r) {
                float acc = bv[r];
                #pragma unroll
                for (int f = 0; f < NF; ++f) acc = fmaf(w[r][f], xv[f], acc);
                (&o.x)[r] = acc;
            }
            *(float4*)(out + (long long)tok * OUTW + q * 4) = o;
        } else {
            const int d = doy[tok];           // wave-uniform
            if (d == 0) {
                o = make_float4(0.f, 0.f, 0.f, 0.f);  // pe row 0 is zeros
            } else {
                const float pos = (float)(d - 1);
                const float a0 = pos * dv0;
                const float a1 = pos * dv1;
                // HW trig: v_fract + v_sin_f32 / v_cos_f32 (~3 instr, err ~2e-5
                // for |a| <= 365 rad; threshold is 0.154)
                o.x = __sinf(a0); o.y = __cosf(a0);
                o.z = __sinf(a1); o.w = __cosf(a1);
            }
            *(float4*)(out + (long long)tok * OUTW + EMB + (q - 64) * 4) = o;
        }
    }
}

extern "C" void kernel_launch(void* const* d_in, const int* in_sizes, int n_in,
                              void* d_out, int out_size, void* d_ws, size_t ws_size,
                              hipStream_t stream) {
    const float* x    = (const float*)d_in[0];  // input_sequence [B,S,NF] fp32
    const int*   doy  = (const int*)  d_in[1];  // doy_sequence   [B,S]    int32
    const float* W    = (const float*)d_in[2];  // W [EMB,NF] fp32
    const float* bias = (const float*)d_in[3];  // b [EMB]    fp32
    float*       out  = (float*)d_out;          // [B,S,2*EMB] fp32

    // 2048 blocks (8/CU) x 4 waves; each block covers 2 tokens/iter ->
    // 32 grid-stride iterations; stores are 16B/lane fully coalesced.
    bert_embed_kernel<<<2048, 256, 0, stream>>>(x, doy, W, bias, out);
}